// Round 9
// baseline (372.186 us; speedup 1.0000x reference)
//
#include <hip/hip_runtime.h>
#include <math.h>

#define D 128
#define NBUCK_MAX 1024     // runtime nbuck = ceil(N/128) = 782
#define NB_EDGE   256      // edge-chunk blocks for count/placement passes
#define CAPB 4096          // static slots per bucket (fill 2048 +- 45 sigma; deterministic input)

typedef unsigned short u16;
typedef unsigned int   u32;
typedef __attribute__((ext_vector_type(8))) short short8;   // 8 bf16 = 4 VGPRs (MFMA A/B frag)
typedef __attribute__((ext_vector_type(4))) float f32x4;    // MFMA C/D frag
typedef __attribute__((ext_vector_type(2))) float f32x2;

static __device__ __forceinline__ u16 f32_to_bf16(float f) {
    u32 u = __builtin_bit_cast(u32, f);
    u32 r = (u + 0x7FFFu + ((u >> 16) & 1u)) >> 16;          // RNE
    return (u16)r;
}
static __device__ __forceinline__ u32 pack_bf16x2(float lo, float hi) {
    return (u32)f32_to_bf16(lo) | ((u32)f32_to_bf16(hi) << 16);
}
static __device__ __forceinline__ float bf16lo_to_f32(u32 v) {
    return __builtin_bit_cast(float, v << 16);
}
static __device__ __forceinline__ float bf16hi_to_f32(u32 v) {
    return __builtin_bit_cast(float, v & 0xFFFF0000u);
}

// ---------------- dispatch 1: bucket_count (blocks 0..NB_EDGE-1) + goff scan + out zero + W pack ----------------
__global__ __launch_bounds__(512) void prep_count(const int* __restrict__ dst, int E, int nbuck,
                                                  int* __restrict__ blockHist,
                                                  const float* __restrict__ W0, const float* __restrict__ W1,
                                                  u16* __restrict__ Wp0, u16* __restrict__ Wp1,
                                                  const int* __restrict__ gsz, int G, int* __restrict__ goff,
                                                  float* __restrict__ outz, int out_n) {
    const int b = blockIdx.x;
    const int tid = threadIdx.x;
    if (b < NB_EDGE) {
        __shared__ int h[NBUCK_MAX];
        for (int i = tid; i < nbuck; i += 512) h[i] = 0;
        __syncthreads();
        int per = (E + NB_EDGE - 1) / NB_EDGE;
        int s = b * per, e = min(E, s + per);
        for (int i = s + tid; i < e; i += 512) atomicAdd(&h[dst[i] >> 7], 1);
        __syncthreads();
        for (int i = tid; i < nbuck; i += 512) blockHist[b * nbuck + i] = h[i];
    } else if (b == NB_EDGE) {
        // exclusive scan of graph sizes -> goff[0..G] (sentinel)
        __shared__ int wsum[8];
        int base = tid * 4;
        int v[4];
        #pragma unroll
        for (int k = 0; k < 4; k++) v[k] = (base + k < G) ? gsz[base + k] : 0;
        int s = v[0] + v[1] + v[2] + v[3];
        int lane = tid & 63;
        int incl = s;
        #pragma unroll
        for (int off = 1; off < 64; off <<= 1) { int t = __shfl_up(incl, off); if (lane >= off) incl += t; }
        int wv = tid >> 6;
        if (lane == 63) wsum[wv] = incl;
        __syncthreads();
        int woff = 0;
        for (int w = 0; w < wv; w++) woff += wsum[w];
        int run = woff + incl - s;
        #pragma unroll
        for (int k = 0; k < 4; k++) {
            if (base + k <= G) goff[base + k] = run;
            run += v[k];
        }
    } else if (b == NB_EDGE + 1) {
        for (int i = tid; i < out_n; i += 512) outz[i] = 0.f;
    } else {
        // W pack: Wp[((nt*4+kt)*64 + lane)*8 + j] = bf16( W[kt*32+(lane>>4)*8+j][nt*16+(lane&15)] )
        int gidx = (b - (NB_EDGE + 2)) * 512 + tid;          // 0 .. 32767
        const float* W = (gidx < 128 * 128) ? W0 : W1;
        u16* Wp = (gidx < 128 * 128) ? Wp0 : Wp1;
        int idx = gidx & (128 * 128 - 1);
        int j = idx & 7, lane = (idx >> 3) & 63, kt = (idx >> 9) & 3, nt = idx >> 11;
        int k = kt * 32 + ((lane >> 4) << 3) + j;
        int n = nt * 16 + (lane & 15);
        Wp[idx] = f32_to_bf16(W[k * 128 + n]);
    }
}

// ---------------- dispatch 2: scan_blocks (per-bucket across NB_EDGE blocks) + node2graph fill ----------------
__global__ __launch_bounds__(256) void scan_fill(int* __restrict__ blockHist, int nbuck,
                                                 int* __restrict__ bucketTotal, int scanB,
                                                 const int* __restrict__ goff, int G,
                                                 int* __restrict__ node2graph, float* __restrict__ invsz) {
    const int tid = threadIdx.x;
    if ((int)blockIdx.x < scanB) {
        int bucket = (blockIdx.x * 256 + tid) >> 6;
        int lane = tid & 63;
        if (bucket >= nbuck) return;
        int carry = 0;
        #pragma unroll
        for (int c = 0; c < NB_EDGE / 64; c++) {
            int idx = (c * 64 + lane) * nbuck + bucket;
            int v = blockHist[idx];
            int incl = v;
            #pragma unroll
            for (int off = 1; off < 64; off <<= 1) { int t = __shfl_up(incl, off); if (lane >= off) incl += t; }
            blockHist[idx] = carry + incl - v;
            carry += __shfl(incl, 63);
        }
        if (lane == 0) bucketTotal[bucket] = carry;
    } else {
        int g = blockIdx.x - scanB;
        if (g >= G) return;
        int start = goff[g], end = goff[g + 1];
        for (int i = start + tid; i < end; i += 256) node2graph[i] = g;
        if (tid == 0) invsz[g] = 1.f / (float)(end - start);
    }
}

// ---------------- dispatch 3: placement via LDS cursors (static bases b*CAPB) ----------------
__global__ __launch_bounds__(512) void bucket_place(const int* __restrict__ src, const int* __restrict__ dst,
                                                    int E, int nbuck, const int* __restrict__ blockHist,
                                                    u32* __restrict__ edgeBuf) {
    __shared__ int cur[NBUCK_MAX];
    int tid = threadIdx.x;
    for (int i = tid; i < nbuck; i += 512)
        cur[i] = i * CAPB + blockHist[blockIdx.x * nbuck + i];
    __syncthreads();
    int per = (E + NB_EDGE - 1) / NB_EDGE;
    int s = blockIdx.x * per, e = min(E, s + per);
    for (int i = s + tid; i < e; i += 512) {
        int d = dst[i];
        int b = d >> 7;
        int pos = atomicAdd(&cur[b], 1);
        edgeBuf[pos] = (u32)src[i] | ((u32)(d & 127) << 20);
    }
}

// ---------------- MFMA GEMM core ----------------
static __device__ __forceinline__ void gemm_body(const short8 af[4], const u16* __restrict__ Wp,
                                                 u16* __restrict__ outb, int N, int row0,
                                                 int tid, int wave, int lane, int quad, int l16,
                                                 u16* Cs) {
    f32x4 acc[8];
    #pragma unroll
    for (int nt = 0; nt < 8; nt++) acc[nt] = (f32x4){0.f, 0.f, 0.f, 0.f};
    #pragma unroll
    for (int kt = 0; kt < 4; kt++) {
        #pragma unroll
        for (int nt = 0; nt < 8; nt++) {
            short8 bf = *(const short8*)(Wp + ((size_t)(nt * 4 + kt) * 64 + lane) * 8);
            acc[nt] = __builtin_amdgcn_mfma_f32_16x16x32_bf16(af[kt], bf, acc[nt], 0, 0, 0);
        }
    }
    // C layout col=lane&15, row=quad*4+reg -> LDS transpose -> coalesced bf16 store
    #pragma unroll
    for (int nt = 0; nt < 8; nt++) {
        #pragma unroll
        for (int r = 0; r < 4; r++) {
            int rl = wave * 16 + quad * 4 + r;
            Cs[rl * 136 + nt * 16 + l16] = f32_to_bf16(acc[nt][r]);
        }
    }
    __syncthreads();
    for (int i = tid; i < 64 * 16; i += 256) {
        int row = i >> 4, chunk = i & 15;
        int grow = row0 + row;
        if (grow <= N)      // row N = zero pad row for agg tail lanes
            *(uint4*)(outb + (size_t)grow * 128 + chunk * 8) =
                *(const uint4*)(Cs + row * 136 + chunk * 8);
    }
}

// ---------------- dispatch 4: csr finalize (blocks 0..nbuck-1) + layer-0 gemm (blocks nbuck..) ----------------
__global__ __launch_bounds__(256) void finalize_gemm0(const u32* __restrict__ edgeBuf,
                                                      const int* __restrict__ bucketTotal,
                                                      int2* __restrict__ rowse, int* __restrict__ col_idx,
                                                      int nbuck,
                                                      const float* __restrict__ A, const u16* __restrict__ Wp,
                                                      u16* __restrict__ outb, int N) {
    __shared__ u16 Cs[64 * 136];
    const int tid = threadIdx.x;
    if ((int)blockIdx.x < nbuck) {
        int* hist = (int*)Cs;            // 128 ints
        int* lcur = ((int*)Cs) + 128;    // 128 ints
        const int b = blockIdx.x;
        const int start = b * CAPB;
        const int end = start + bucketTotal[b];
        if (tid < 128) hist[tid] = 0;
        __syncthreads();
        for (int i = start + tid; i < end; i += 256)
            atomicAdd(&hist[edgeBuf[i] >> 20], 1);
        __syncthreads();
        if (tid < 64) {
            int v0 = hist[tid * 2], v1 = hist[tid * 2 + 1];
            int s = v0 + v1;
            int incl = s;
            #pragma unroll
            for (int off = 1; off < 64; off <<= 1) { int t = __shfl_up(incl, off); if (tid >= off) incl += t; }
            int excl = incl - s;
            lcur[tid * 2] = excl;
            lcur[tid * 2 + 1] = excl + v0;
            int node = b * 128 + tid * 2;
            int st = start + excl;
            if (node < N) rowse[node] = make_int2(st, st + v0);
            if (node + 1 < N) rowse[node + 1] = make_int2(st + v0, st + v0 + v1);
        }
        __syncthreads();
        for (int i = start + tid; i < end; i += 256) {
            u32 p = edgeBuf[i];
            int pos = atomicAdd(&lcur[p >> 20], 1);
            col_idx[start + pos] = (int)(p & 0xFFFFFu);
        }
    } else {
        const int bid = blockIdx.x - nbuck;
        const int wave = tid >> 6, lane = tid & 63, quad = lane >> 4, l16 = lane & 15;
        const int row0 = bid * 64;
        const int arow = row0 + wave * 16 + l16;
        union { u32 u[4]; short8 s; } cv;
        short8 af[4];
        if (arow < N) {
            const float* ab = A + (size_t)arow * 128 + quad * 8;
            #pragma unroll
            for (int kt = 0; kt < 4; kt++) {
                float4 x0 = *(const float4*)(ab + kt * 32);
                float4 x1 = *(const float4*)(ab + kt * 32 + 4);
                cv.u[0] = pack_bf16x2(x0.x, x0.y);
                cv.u[1] = pack_bf16x2(x0.z, x0.w);
                cv.u[2] = pack_bf16x2(x1.x, x1.y);
                cv.u[3] = pack_bf16x2(x1.z, x1.w);
                af[kt] = cv.s;
            }
        } else {
            short8 z = {0, 0, 0, 0, 0, 0, 0, 0};
            #pragma unroll
            for (int kt = 0; kt < 4; kt++) af[kt] = z;
        }
        gemm_body(af, Wp, outb, N, row0, tid, wave, lane, quad, l16, Cs);
    }
}

// dispatch 6: layer-1 GEMM, bf16 A
__global__ __launch_bounds__(256) void gemm_mfma(const u16* __restrict__ A, const u16* __restrict__ Wp,
                                                 u16* __restrict__ outb, int N) {
    __shared__ u16 Cs[64 * 136];
    const int tid = threadIdx.x;
    const int wave = tid >> 6, lane = tid & 63, quad = lane >> 4, l16 = lane & 15;
    const int row0 = blockIdx.x * 64;
    const int arow = row0 + wave * 16 + l16;
    short8 af[4];
    if (arow < N) {
        const u16* ab = A + (size_t)arow * 128 + quad * 8;
        #pragma unroll
        for (int kt = 0; kt < 4; kt++) af[kt] = *(const short8*)(ab + kt * 32);
    } else {
        short8 z = {0, 0, 0, 0, 0, 0, 0, 0};
        #pragma unroll
        for (int kt = 0; kt < 4; kt++) af[kt] = z;
    }
    gemm_body(af, Wp, outb, N, row0, tid, wave, lane, quad, l16, Cs);
}

// ---------------- shared gather core: returns relu(sum + self + bias) slice in r[8] ----------------
static __device__ __forceinline__ void add_row(f32x2* acc, uint4 u) {
    acc[0] += (f32x2){bf16lo_to_f32(u.x), bf16hi_to_f32(u.x)};
    acc[1] += (f32x2){bf16lo_to_f32(u.y), bf16hi_to_f32(u.y)};
    acc[2] += (f32x2){bf16lo_to_f32(u.z), bf16hi_to_f32(u.z)};
    acc[3] += (f32x2){bf16lo_to_f32(u.w), bf16hi_to_f32(u.w)};
}

static __device__ __forceinline__ void gather_core(const u16* __restrict__ xwb, const int2* __restrict__ rowse,
                                                   const int* __restrict__ col_idx, const float* __restrict__ bias,
                                                   int wid, int lane, int N, int q, int d8, float r[8]) {
    f32x2 acc[4];
    #pragma unroll
    for (int t = 0; t < 4; t++) acc[t] = (f32x2){0.f, 0.f};
    int2 se = rowse[wid];
    int start = se.x, end = se.y;
    for (int e = start; e < end; e += 64) {
        int idx = e + lane;
        int j = (idx < end) ? col_idx[idx] : N;   // tail -> shared zero row
        int cnt = min(64, end - e);
        for (int i = 0; i < cnt; i += 16) {
            int j0 = __shfl(j, i + q);
            int j1 = __shfl(j, i + 4 + q);
            int j2 = __shfl(j, i + 8 + q);
            int j3 = __shfl(j, i + 12 + q);
            uint4 r0 = *(const uint4*)(xwb + (size_t)j0 * D + d8);
            uint4 r1 = *(const uint4*)(xwb + (size_t)j1 * D + d8);
            uint4 r2 = *(const uint4*)(xwb + (size_t)j2 * D + d8);
            uint4 r3 = *(const uint4*)(xwb + (size_t)j3 * D + d8);
            add_row(acc, r0);
            add_row(acc, r1);
            add_row(acc, r2);
            add_row(acc, r3);
        }
    }
    float av[8] = {acc[0].x, acc[0].y, acc[1].x, acc[1].y, acc[2].x, acc[2].y, acc[3].x, acc[3].y};
    #pragma unroll
    for (int t = 0; t < 8; t++) {
        av[t] += __shfl_xor(av[t], 16);
        av[t] += __shfl_xor(av[t], 32);
    }
    uint4 sv = *(const uint4*)(xwb + (size_t)wid * D + d8);
    float4 ba = *(const float4*)(bias + d8);
    float4 bb = *(const float4*)(bias + d8 + 4);
    r[0] = fmaxf(av[0] + bf16lo_to_f32(sv.x) + ba.x, 0.f);
    r[1] = fmaxf(av[1] + bf16hi_to_f32(sv.x) + ba.y, 0.f);
    r[2] = fmaxf(av[2] + bf16lo_to_f32(sv.y) + ba.z, 0.f);
    r[3] = fmaxf(av[3] + bf16hi_to_f32(sv.y) + ba.w, 0.f);
    r[4] = fmaxf(av[4] + bf16lo_to_f32(sv.z) + bb.x, 0.f);
    r[5] = fmaxf(av[5] + bf16hi_to_f32(sv.z) + bb.y, 0.f);
    r[6] = fmaxf(av[6] + bf16lo_to_f32(sv.w) + bb.z, 0.f);
    r[7] = fmaxf(av[7] + bf16hi_to_f32(sv.w) + bb.w, 0.f);
}

// dispatch 5: layer-1 aggregate, stores bf16 h
__global__ __launch_bounds__(256) void agg_relu(const u16* __restrict__ xwb, const int2* __restrict__ rowse,
                                                const int* __restrict__ col_idx, const float* __restrict__ bias,
                                                u16* __restrict__ outh, int N) {
    int wid = (blockIdx.x * 256 + threadIdx.x) >> 6;
    int lane = threadIdx.x & 63;
    if (wid >= N) return;
    const int q = lane >> 4;
    const int d8 = (lane & 15) * 8;
    float r[8];
    gather_core(xwb, rowse, col_idx, bias, wid, lane, N, q, d8, r);
    if (q == 0) {
        uint4 o;
        o.x = pack_bf16x2(r[0], r[1]);
        o.y = pack_bf16x2(r[2], r[3]);
        o.z = pack_bf16x2(r[4], r[5]);
        o.w = pack_bf16x2(r[6], r[7]);
        *(uint4*)(outh + (size_t)wid * D + d8) = o;
    }
}

// dispatch 7: layer-2 aggregate fused with head + per-graph mean (atomic accumulate)
// quarter q computes tasks t=3q..3q+2: partial over its 8 dims, shfl-reduce over 16 lanes,
// l16==0 lane does sigmoid * 1/size and atomicAdd into out[g][t].
__global__ __launch_bounds__(256) void agg_head(const u16* __restrict__ xwb, const int2* __restrict__ rowse,
                                                const int* __restrict__ col_idx, const float* __restrict__ bias,
                                                const int* __restrict__ node2graph, const float* __restrict__ invsz,
                                                const float* __restrict__ Wf, const float* __restrict__ bfv,
                                                float* __restrict__ out, int N) {
    int wid = (blockIdx.x * 256 + threadIdx.x) >> 6;
    int lane = threadIdx.x & 63;
    if (wid >= N) return;
    const int q = lane >> 4;
    const int d8 = (lane & 15) * 8;
    float r[8];
    gather_core(xwb, rowse, col_idx, bias, wid, lane, N, q, d8, r);
    // head: tasks t0..t0+2 for this quarter; Wf is [128][12] row-major (L1-resident, 6 KB)
    const int t0 = 3 * q;
    float p0 = 0.f, p1 = 0.f, p2 = 0.f;
    #pragma unroll
    for (int k = 0; k < 8; k++) {
        const float* wr = Wf + (d8 + k) * 12 + t0;
        p0 += r[k] * wr[0];
        p1 += r[k] * wr[1];
        p2 += r[k] * wr[2];
    }
    #pragma unroll
    for (int m = 1; m <= 8; m <<= 1) {
        p0 += __shfl_xor(p0, m);
        p1 += __shfl_xor(p1, m);
        p2 += __shfl_xor(p2, m);
    }
    if ((lane & 15) == 0) {
        int g = node2graph[wid];
        float is = invsz[g];
        float s0 = is / (1.f + __expf(-(p0 + bfv[t0])));
        float s1 = is / (1.f + __expf(-(p1 + bfv[t0 + 1])));
        float s2 = is / (1.f + __expf(-(p2 + bfv[t0 + 2])));
        float* o = out + (size_t)g * 12 + t0;
        atomicAdd(o, s0);
        atomicAdd(o + 1, s1);
        atomicAdd(o + 2, s2);
    }
}

// ---------------- launch ----------------

extern "C" void kernel_launch(void* const* d_in, const int* in_sizes, int n_in,
                              void* d_out, int out_size, void* d_ws, size_t ws_size,
                              hipStream_t stream) {
    const float* X   = (const float*)d_in[0];
    const int* edges = (const int*)d_in[1];
    const int* gsz   = (const int*)d_in[2];
    const float* W0  = (const float*)d_in[3];
    const float* b0  = (const float*)d_in[4];
    const float* W1  = (const float*)d_in[5];
    const float* b1  = (const float*)d_in[6];
    const float* Wf  = (const float*)d_in[7];
    const float* bfv = (const float*)d_in[8];
    float* out = (float*)d_out;

    const int N = in_sizes[0] / D;       // 100000
    const int E = in_sizes[1] / 2;       // 1600000
    const int G = in_sizes[2];           // 1000
    const int* esrc = edges;
    const int* edst = edges + E;
    const int nbuck = (N + 127) >> 7;    // 782

    // workspace layout (xwb/hb get N+64 rows: row N is the zero pad row)
    char* ws = (char*)d_ws;
    char* p = ws;
    u16* xwb     = (u16*)p;  p += (((size_t)(N + 64) * D * 2) + 255) & ~255ull;
    u16* hb      = (u16*)p;  p += (((size_t)(N + 64) * D * 2) + 255) & ~255ull;
    u16* Wp0     = (u16*)p;  p += ((size_t)128 * 128 * 2 + 255) & ~255ull;
    u16* Wp1     = (u16*)p;  p += ((size_t)128 * 128 * 2 + 255) & ~255ull;
    u32* edgeBuf = (u32*)p;  p += (((size_t)nbuck * CAPB * 4) + 255) & ~255ull;   // 12.8 MB
    int* col_idx = (int*)p;  p += (((size_t)nbuck * CAPB * 4) + 255) & ~255ull;   // 12.8 MB
    int2* rowse  = (int2*)p; p += (((size_t)N * 8) + 255) & ~255ull;
    int* node2graph = (int*)p; p += (((size_t)N * 4) + 255) & ~255ull;
    int* blockHist   = (int*)p; p += ((size_t)NB_EDGE * NBUCK_MAX * 4 + 255) & ~255ull;
    int* bucketTotal = (int*)p; p += ((size_t)NBUCK_MAX * 4 + 255) & ~255ull;
    float* invsz     = (float*)p; p += ((size_t)NBUCK_MAX * 4 + 255) & ~255ull;
    int* goff        = (int*)p;

    // 1: bucket count + goff scan + out zero + W pack
    prep_count<<<NB_EDGE + 2 + 64, 512, 0, stream>>>(edst, E, nbuck, blockHist,
                                                     W0, W1, Wp0, Wp1, gsz, G, goff, out, out_size);
    // 2: per-bucket block-scan + node2graph/invsz fill
    const int scanB = (nbuck * 64 + 255) / 256;
    scan_fill<<<scanB + G, 256, 0, stream>>>(blockHist, nbuck, bucketTotal, scanB, goff, G, node2graph, invsz);
    // 3: placement (LDS cursors, static bases)
    bucket_place<<<NB_EDGE, 512, 0, stream>>>(esrc, edst, E, nbuck, blockHist, edgeBuf);
    // 4: per-bucket CSR finalize + layer-0 GEMM (fp32 A, fused cast)
    const int gemmGrid = (N + 63) / 64;
    finalize_gemm0<<<nbuck + gemmGrid, 256, 0, stream>>>(edgeBuf, bucketTotal, rowse, col_idx, nbuck,
                                                         X, Wp0, xwb, N);
    // 5: layer-1 aggregate
    agg_relu<<<(N * 64 + 255) / 256, 256, 0, stream>>>(xwb, rowse, col_idx, b0, hb, N);
    // 6: layer-1 GEMM
    gemm_mfma<<<gemmGrid, 256, 0, stream>>>(hb, Wp1, xwb, N);
    // 7: layer-2 aggregate fused with head + readout
    agg_head<<<(N * 64 + 255) / 256, 256, 0, stream>>>(xwb, rowse, col_idx, b1, node2graph, invsz,
                                                       Wf, bfv, out, N);
}

// Round 10
// 348.550 us; speedup vs baseline: 1.0678x; 1.0678x over previous
//
#include <hip/hip_runtime.h>
#include <math.h>

#define D 128
#define NBUCK_MAX 1024     // runtime nbuck = ceil(N/128) = 782
#define NB_EDGE   256      // edge-chunk blocks for count/placement passes
#define CAPB 4096          // static slots per bucket (fill 2048 +- 45 sigma; deterministic input)

typedef unsigned short u16;
typedef unsigned int   u32;
typedef __attribute__((ext_vector_type(8))) short short8;   // 8 bf16 = 4 VGPRs (MFMA A/B frag)
typedef __attribute__((ext_vector_type(4))) float f32x4;    // MFMA C/D frag
typedef __attribute__((ext_vector_type(2))) float f32x2;

static __device__ __forceinline__ u16 f32_to_bf16(float f) {
    u32 u = __builtin_bit_cast(u32, f);
    u32 r = (u + 0x7FFFu + ((u >> 16) & 1u)) >> 16;          // RNE
    return (u16)r;
}
static __device__ __forceinline__ u32 pack_bf16x2(float lo, float hi) {
    return (u32)f32_to_bf16(lo) | ((u32)f32_to_bf16(hi) << 16);
}
static __device__ __forceinline__ float bf16lo_to_f32(u32 v) {
    return __builtin_bit_cast(float, v << 16);
}
static __device__ __forceinline__ float bf16hi_to_f32(u32 v) {
    return __builtin_bit_cast(float, v & 0xFFFF0000u);
}

// ---------------- dispatch 1: bucket_count (blocks 0..NB_EDGE-1) + goff scan + W pack ----------------
__global__ __launch_bounds__(512) void prep_count(const int* __restrict__ dst, int E, int nbuck,
                                                  int* __restrict__ blockHist,
                                                  const float* __restrict__ W0, const float* __restrict__ W1,
                                                  u16* __restrict__ Wp0, u16* __restrict__ Wp1,
                                                  const int* __restrict__ gsz, int G, int* __restrict__ goff) {
    const int b = blockIdx.x;
    const int tid = threadIdx.x;
    if (b < NB_EDGE) {
        __shared__ int h[NBUCK_MAX];
        for (int i = tid; i < nbuck; i += 512) h[i] = 0;
        __syncthreads();
        int per = (E + NB_EDGE - 1) / NB_EDGE;
        int s = b * per, e = min(E, s + per);
        for (int i = s + tid; i < e; i += 512) atomicAdd(&h[dst[i] >> 7], 1);
        __syncthreads();
        for (int i = tid; i < nbuck; i += 512) blockHist[b * nbuck + i] = h[i];
    } else if (b == NB_EDGE) {
        // exclusive scan of graph sizes -> goff[0..G] (sentinel)
        __shared__ int wsum[8];
        int base = tid * 4;
        int v[4];
        #pragma unroll
        for (int k = 0; k < 4; k++) v[k] = (base + k < G) ? gsz[base + k] : 0;
        int s = v[0] + v[1] + v[2] + v[3];
        int lane = tid & 63;
        int incl = s;
        #pragma unroll
        for (int off = 1; off < 64; off <<= 1) { int t = __shfl_up(incl, off); if (lane >= off) incl += t; }
        int wv = tid >> 6;
        if (lane == 63) wsum[wv] = incl;
        __syncthreads();
        int woff = 0;
        for (int w = 0; w < wv; w++) woff += wsum[w];
        int run = woff + incl - s;
        #pragma unroll
        for (int k = 0; k < 4; k++) {
            if (base + k <= G) goff[base + k] = run;
            run += v[k];
        }
    } else {
        // W pack: Wp[((nt*4+kt)*64 + lane)*8 + j] = bf16( W[kt*32+(lane>>4)*8+j][nt*16+(lane&15)] )
        int gidx = (b - (NB_EDGE + 1)) * 512 + tid;          // 0 .. 32767
        const float* W = (gidx < 128 * 128) ? W0 : W1;
        u16* Wp = (gidx < 128 * 128) ? Wp0 : Wp1;
        int idx = gidx & (128 * 128 - 1);
        int j = idx & 7, lane = (idx >> 3) & 63, kt = (idx >> 9) & 3, nt = idx >> 11;
        int k = kt * 32 + ((lane >> 4) << 3) + j;
        int n = nt * 16 + (lane & 15);
        Wp[idx] = f32_to_bf16(W[k * 128 + n]);
    }
}

// ---------------- dispatch 2: scan_blocks (per-bucket exclusive scan across NB_EDGE blocks) ----------------
__global__ __launch_bounds__(256) void scan_blocks(int* __restrict__ blockHist, int nbuck,
                                                   int* __restrict__ bucketTotal) {
    int bucket = (blockIdx.x * 256 + threadIdx.x) >> 6;
    int lane = threadIdx.x & 63;
    if (bucket >= nbuck) return;
    int carry = 0;
    #pragma unroll
    for (int c = 0; c < NB_EDGE / 64; c++) {
        int idx = (c * 64 + lane) * nbuck + bucket;
        int v = blockHist[idx];
        int incl = v;
        #pragma unroll
        for (int off = 1; off < 64; off <<= 1) { int t = __shfl_up(incl, off); if (lane >= off) incl += t; }
        blockHist[idx] = carry + incl - v;
        carry += __shfl(incl, 63);
    }
    if (lane == 0) bucketTotal[bucket] = carry;
}

// ---------------- dispatch 3: placement via LDS cursors (static bases b*CAPB) ----------------
__global__ __launch_bounds__(512) void bucket_place(const int* __restrict__ src, const int* __restrict__ dst,
                                                    int E, int nbuck, const int* __restrict__ blockHist,
                                                    u32* __restrict__ edgeBuf) {
    __shared__ int cur[NBUCK_MAX];
    int tid = threadIdx.x;
    for (int i = tid; i < nbuck; i += 512)
        cur[i] = i * CAPB + blockHist[blockIdx.x * nbuck + i];
    __syncthreads();
    int per = (E + NB_EDGE - 1) / NB_EDGE;
    int s = blockIdx.x * per, e = min(E, s + per);
    for (int i = s + tid; i < e; i += 512) {
        int d = dst[i];
        int b = d >> 7;
        int pos = atomicAdd(&cur[b], 1);
        edgeBuf[pos] = (u32)src[i] | ((u32)(d & 127) << 20);
    }
}

// ---------------- MFMA GEMM core ----------------
static __device__ __forceinline__ void gemm_body(const short8 af[4], const u16* __restrict__ Wp,
                                                 u16* __restrict__ outb, int N, int row0,
                                                 int tid, int wave, int lane, int quad, int l16,
                                                 u16* Cs) {
    f32x4 acc[8];
    #pragma unroll
    for (int nt = 0; nt < 8; nt++) acc[nt] = (f32x4){0.f, 0.f, 0.f, 0.f};
    #pragma unroll
    for (int kt = 0; kt < 4; kt++) {
        #pragma unroll
        for (int nt = 0; nt < 8; nt++) {
            short8 bf = *(const short8*)(Wp + ((size_t)(nt * 4 + kt) * 64 + lane) * 8);
            acc[nt] = __builtin_amdgcn_mfma_f32_16x16x32_bf16(af[kt], bf, acc[nt], 0, 0, 0);
        }
    }
    // C layout col=lane&15, row=quad*4+reg -> LDS transpose -> coalesced bf16 store
    #pragma unroll
    for (int nt = 0; nt < 8; nt++) {
        #pragma unroll
        for (int r = 0; r < 4; r++) {
            int rl = wave * 16 + quad * 4 + r;
            Cs[rl * 136 + nt * 16 + l16] = f32_to_bf16(acc[nt][r]);
        }
    }
    __syncthreads();
    for (int i = tid; i < 64 * 16; i += 256) {
        int row = i >> 4, chunk = i & 15;
        int grow = row0 + row;
        if (grow <= N)      // row N = zero pad row for agg tail lanes
            *(uint4*)(outb + (size_t)grow * 128 + chunk * 8) =
                *(const uint4*)(Cs + row * 136 + chunk * 8);
    }
}

// ---------------- dispatch 4: csr finalize (blocks 0..nbuck-1) + layer-0 gemm (blocks nbuck..) ----------------
__global__ __launch_bounds__(256) void finalize_gemm0(const u32* __restrict__ edgeBuf,
                                                      const int* __restrict__ bucketTotal,
                                                      int2* __restrict__ rowse, int* __restrict__ col_idx,
                                                      int nbuck,
                                                      const float* __restrict__ A, const u16* __restrict__ Wp,
                                                      u16* __restrict__ outb, int N) {
    __shared__ u16 Cs[64 * 136];
    const int tid = threadIdx.x;
    if ((int)blockIdx.x < nbuck) {
        int* hist = (int*)Cs;            // 128 ints
        int* lcur = ((int*)Cs) + 128;    // 128 ints
        const int b = blockIdx.x;
        const int start = b * CAPB;
        const int end = start + bucketTotal[b];
        if (tid < 128) hist[tid] = 0;
        __syncthreads();
        for (int i = start + tid; i < end; i += 256)
            atomicAdd(&hist[edgeBuf[i] >> 20], 1);
        __syncthreads();
        if (tid < 64) {
            int v0 = hist[tid * 2], v1 = hist[tid * 2 + 1];
            int s = v0 + v1;
            int incl = s;
            #pragma unroll
            for (int off = 1; off < 64; off <<= 1) { int t = __shfl_up(incl, off); if (tid >= off) incl += t; }
            int excl = incl - s;
            lcur[tid * 2] = excl;
            lcur[tid * 2 + 1] = excl + v0;
            int node = b * 128 + tid * 2;
            int st = start + excl;
            if (node < N) rowse[node] = make_int2(st, st + v0);
            if (node + 1 < N) rowse[node + 1] = make_int2(st + v0, st + v0 + v1);
        }
        __syncthreads();
        for (int i = start + tid; i < end; i += 256) {
            u32 p = edgeBuf[i];
            int pos = atomicAdd(&lcur[p >> 20], 1);
            col_idx[start + pos] = (int)(p & 0xFFFFFu);
        }
    } else {
        const int bid = blockIdx.x - nbuck;
        const int wave = tid >> 6, lane = tid & 63, quad = lane >> 4, l16 = lane & 15;
        const int row0 = bid * 64;
        const int arow = row0 + wave * 16 + l16;
        union { u32 u[4]; short8 s; } cv;
        short8 af[4];
        if (arow < N) {
            const float* ab = A + (size_t)arow * 128 + quad * 8;
            #pragma unroll
            for (int kt = 0; kt < 4; kt++) {
                float4 x0 = *(const float4*)(ab + kt * 32);
                float4 x1 = *(const float4*)(ab + kt * 32 + 4);
                cv.u[0] = pack_bf16x2(x0.x, x0.y);
                cv.u[1] = pack_bf16x2(x0.z, x0.w);
                cv.u[2] = pack_bf16x2(x1.x, x1.y);
                cv.u[3] = pack_bf16x2(x1.z, x1.w);
                af[kt] = cv.s;
            }
        } else {
            short8 z = {0, 0, 0, 0, 0, 0, 0, 0};
            #pragma unroll
            for (int kt = 0; kt < 4; kt++) af[kt] = z;
        }
        gemm_body(af, Wp, outb, N, row0, tid, wave, lane, quad, l16, Cs);
    }
}

// dispatch 6: layer-1 GEMM, bf16 A
__global__ __launch_bounds__(256) void gemm_mfma(const u16* __restrict__ A, const u16* __restrict__ Wp,
                                                 u16* __restrict__ outb, int N) {
    __shared__ u16 Cs[64 * 136];
    const int tid = threadIdx.x;
    const int wave = tid >> 6, lane = tid & 63, quad = lane >> 4, l16 = lane & 15;
    const int row0 = blockIdx.x * 64;
    const int arow = row0 + wave * 16 + l16;
    short8 af[4];
    if (arow < N) {
        const u16* ab = A + (size_t)arow * 128 + quad * 8;
        #pragma unroll
        for (int kt = 0; kt < 4; kt++) af[kt] = *(const short8*)(ab + kt * 32);
    } else {
        short8 z = {0, 0, 0, 0, 0, 0, 0, 0};
        #pragma unroll
        for (int kt = 0; kt < 4; kt++) af[kt] = z;
    }
    gemm_body(af, Wp, outb, N, row0, tid, wave, lane, quad, l16, Cs);
}

// ---------------- shared gather core: returns relu(sum + self + bias) slice in r[8] ----------------
static __device__ __forceinline__ void add_row(f32x2* acc, uint4 u) {
    acc[0] += (f32x2){bf16lo_to_f32(u.x), bf16hi_to_f32(u.x)};
    acc[1] += (f32x2){bf16lo_to_f32(u.y), bf16hi_to_f32(u.y)};
    acc[2] += (f32x2){bf16lo_to_f32(u.z), bf16hi_to_f32(u.z)};
    acc[3] += (f32x2){bf16lo_to_f32(u.w), bf16hi_to_f32(u.w)};
}

static __device__ __forceinline__ void gather_core(const u16* __restrict__ xwb, const int2* __restrict__ rowse,
                                                   const int* __restrict__ col_idx, const float* __restrict__ bias,
                                                   int wid, int lane, int N, int q, int d8, float r[8]) {
    f32x2 acc[4];
    #pragma unroll
    for (int t = 0; t < 4; t++) acc[t] = (f32x2){0.f, 0.f};
    int2 se = rowse[wid];
    int start = se.x, end = se.y;
    for (int e = start; e < end; e += 64) {
        int idx = e + lane;
        int j = (idx < end) ? col_idx[idx] : N;   // tail -> shared zero row
        int cnt = min(64, end - e);
        for (int i = 0; i < cnt; i += 16) {
            int j0 = __shfl(j, i + q);
            int j1 = __shfl(j, i + 4 + q);
            int j2 = __shfl(j, i + 8 + q);
            int j3 = __shfl(j, i + 12 + q);
            uint4 r0 = *(const uint4*)(xwb + (size_t)j0 * D + d8);
            uint4 r1 = *(const uint4*)(xwb + (size_t)j1 * D + d8);
            uint4 r2 = *(const uint4*)(xwb + (size_t)j2 * D + d8);
            uint4 r3 = *(const uint4*)(xwb + (size_t)j3 * D + d8);
            add_row(acc, r0);
            add_row(acc, r1);
            add_row(acc, r2);
            add_row(acc, r3);
        }
    }
    float av[8] = {acc[0].x, acc[0].y, acc[1].x, acc[1].y, acc[2].x, acc[2].y, acc[3].x, acc[3].y};
    #pragma unroll
    for (int t = 0; t < 8; t++) {
        av[t] += __shfl_xor(av[t], 16);
        av[t] += __shfl_xor(av[t], 32);
    }
    uint4 sv = *(const uint4*)(xwb + (size_t)wid * D + d8);
    float4 ba = *(const float4*)(bias + d8);
    float4 bb = *(const float4*)(bias + d8 + 4);
    r[0] = fmaxf(av[0] + bf16lo_to_f32(sv.x) + ba.x, 0.f);
    r[1] = fmaxf(av[1] + bf16hi_to_f32(sv.x) + ba.y, 0.f);
    r[2] = fmaxf(av[2] + bf16lo_to_f32(sv.y) + ba.z, 0.f);
    r[3] = fmaxf(av[3] + bf16hi_to_f32(sv.y) + ba.w, 0.f);
    r[4] = fmaxf(av[4] + bf16lo_to_f32(sv.z) + bb.x, 0.f);
    r[5] = fmaxf(av[5] + bf16hi_to_f32(sv.z) + bb.y, 0.f);
    r[6] = fmaxf(av[6] + bf16lo_to_f32(sv.w) + bb.z, 0.f);
    r[7] = fmaxf(av[7] + bf16hi_to_f32(sv.w) + bb.w, 0.f);
}

// dispatch 5: layer-1 aggregate, stores bf16 h
__global__ __launch_bounds__(256) void agg_relu(const u16* __restrict__ xwb, const int2* __restrict__ rowse,
                                                const int* __restrict__ col_idx, const float* __restrict__ bias,
                                                u16* __restrict__ outh, int N) {
    int wid = (blockIdx.x * 256 + threadIdx.x) >> 6;
    int lane = threadIdx.x & 63;
    if (wid >= N) return;
    const int q = lane >> 4;
    const int d8 = (lane & 15) * 8;
    float r[8];
    gather_core(xwb, rowse, col_idx, bias, wid, lane, N, q, d8, r);
    if (q == 0) {
        uint4 o;
        o.x = pack_bf16x2(r[0], r[1]);
        o.y = pack_bf16x2(r[2], r[3]);
        o.z = pack_bf16x2(r[4], r[5]);
        o.w = pack_bf16x2(r[6], r[7]);
        *(uint4*)(outh + (size_t)wid * D + d8) = o;
    }
}

// dispatch 7: layer-2 aggregate fused with head; writes sigmoid logits to out12[node][12]
// quarter q computes tasks t=3q..3q+2; lane l16==0 of each quarter stores 3 contiguous floats.
__global__ __launch_bounds__(256) void agg_head(const u16* __restrict__ xwb, const int2* __restrict__ rowse,
                                                const int* __restrict__ col_idx, const float* __restrict__ bias,
                                                const float* __restrict__ Wf, const float* __restrict__ bfv,
                                                float* __restrict__ out12, int N) {
    int wid = (blockIdx.x * 256 + threadIdx.x) >> 6;
    int lane = threadIdx.x & 63;
    if (wid >= N) return;
    const int q = lane >> 4;
    const int d8 = (lane & 15) * 8;
    float r[8];
    gather_core(xwb, rowse, col_idx, bias, wid, lane, N, q, d8, r);
    // head: tasks t0..t0+2 for this quarter; Wf is [128][12] row-major (L1-resident, 6 KB)
    const int t0 = 3 * q;
    float p0 = 0.f, p1 = 0.f, p2 = 0.f;
    #pragma unroll
    for (int k = 0; k < 8; k++) {
        const float* wr = Wf + (d8 + k) * 12 + t0;
        p0 += r[k] * wr[0];
        p1 += r[k] * wr[1];
        p2 += r[k] * wr[2];
    }
    #pragma unroll
    for (int m = 1; m <= 8; m <<= 1) {
        p0 += __shfl_xor(p0, m);
        p1 += __shfl_xor(p1, m);
        p2 += __shfl_xor(p2, m);
    }
    if ((lane & 15) == 0) {
        float s0 = 1.f / (1.f + __expf(-(p0 + bfv[t0])));
        float s1 = 1.f / (1.f + __expf(-(p1 + bfv[t0 + 1])));
        float s2 = 1.f / (1.f + __expf(-(p2 + bfv[t0 + 2])));
        float* o = out12 + (size_t)wid * 12 + t0;
        o[0] = s0; o[1] = s1; o[2] = s2;
    }
}

// dispatch 8: per-graph mean over out12
__global__ __launch_bounds__(128) void graph_mean(const float* __restrict__ out12, const int* __restrict__ goff,
                                                  float* __restrict__ out, int G) {
    __shared__ float partial[120];
    int g = blockIdx.x;
    int tid = threadIdx.x;
    int start = goff[g];
    int size = goff[g + 1] - start;
    if (tid < 120) {
        int t = tid % 12, chunk = tid / 12;
        float s = 0.f;
        for (int i = chunk; i < size; i += 10)
            s += out12[(size_t)(start + i) * 12 + t];
        partial[tid] = s;
    }
    __syncthreads();
    if (tid < 12) {
        float tot = 0.f;
        #pragma unroll
        for (int c = 0; c < 10; c++) tot += partial[c * 12 + tid];
        out[(size_t)g * 12 + tid] = tot / (float)size;
    }
}

// ---------------- launch ----------------

extern "C" void kernel_launch(void* const* d_in, const int* in_sizes, int n_in,
                              void* d_out, int out_size, void* d_ws, size_t ws_size,
                              hipStream_t stream) {
    const float* X   = (const float*)d_in[0];
    const int* edges = (const int*)d_in[1];
    const int* gsz   = (const int*)d_in[2];
    const float* W0  = (const float*)d_in[3];
    const float* b0  = (const float*)d_in[4];
    const float* W1  = (const float*)d_in[5];
    const float* b1  = (const float*)d_in[6];
    const float* Wf  = (const float*)d_in[7];
    const float* bfv = (const float*)d_in[8];
    float* out = (float*)d_out;

    const int N = in_sizes[0] / D;       // 100000
    const int E = in_sizes[1] / 2;       // 1600000
    const int G = in_sizes[2];           // 1000
    const int* esrc = edges;
    const int* edst = edges + E;
    const int nbuck = (N + 127) >> 7;    // 782

    // workspace layout (xwb/hb get N+64 rows: row N is the zero pad row)
    char* ws = (char*)d_ws;
    char* p = ws;
    u16* xwb     = (u16*)p;  p += (((size_t)(N + 64) * D * 2) + 255) & ~255ull;
    u16* hb      = (u16*)p;  p += (((size_t)(N + 64) * D * 2) + 255) & ~255ull;
    u16* Wp0     = (u16*)p;  p += ((size_t)128 * 128 * 2 + 255) & ~255ull;
    u16* Wp1     = (u16*)p;  p += ((size_t)128 * 128 * 2 + 255) & ~255ull;
    u32* edgeBuf = (u32*)p;  p += (((size_t)nbuck * CAPB * 4) + 255) & ~255ull;   // 12.8 MB
    int* col_idx = (int*)p;  p += (((size_t)nbuck * CAPB * 4) + 255) & ~255ull;   // 12.8 MB
    int2* rowse  = (int2*)p; p += (((size_t)N * 8) + 255) & ~255ull;
    float* out12 = (float*)p; p += (((size_t)N * 12 * 4) + 255) & ~255ull;        // 4.8 MB
    int* blockHist   = (int*)p; p += ((size_t)NB_EDGE * NBUCK_MAX * 4 + 255) & ~255ull;
    int* bucketTotal = (int*)p; p += ((size_t)NBUCK_MAX * 4 + 255) & ~255ull;
    int* goff        = (int*)p;

    // 1: bucket count + goff scan + W pack
    prep_count<<<NB_EDGE + 1 + 64, 512, 0, stream>>>(edst, E, nbuck, blockHist,
                                                     W0, W1, Wp0, Wp1, gsz, G, goff);
    // 2: per-bucket block-scan
    scan_blocks<<<(nbuck * 64 + 255) / 256, 256, 0, stream>>>(blockHist, nbuck, bucketTotal);
    // 3: placement (LDS cursors, static bases)
    bucket_place<<<NB_EDGE, 512, 0, stream>>>(esrc, edst, E, nbuck, blockHist, edgeBuf);
    // 4: per-bucket CSR finalize + layer-0 GEMM (fp32 A, fused cast)
    const int gemmGrid = (N + 63) / 64;
    finalize_gemm0<<<nbuck + gemmGrid, 256, 0, stream>>>(edgeBuf, bucketTotal, rowse, col_idx, nbuck,
                                                         X, Wp0, xwb, N);
    // 5: layer-1 aggregate
    agg_relu<<<(N * 64 + 255) / 256, 256, 0, stream>>>(xwb, rowse, col_idx, b0, hb, N);
    // 6: layer-1 GEMM
    gemm_mfma<<<gemmGrid, 256, 0, stream>>>(hb, Wp1, xwb, N);
    // 7: layer-2 aggregate fused with head -> out12 (coalesced per-node writes, no atomics)
    agg_head<<<(N * 64 + 255) / 256, 256, 0, stream>>>(xwb, rowse, col_idx, b1, Wf, bfv, out12, N);
    // 8: per-graph mean
    graph_mean<<<G, 128, 0, stream>>>(out12, goff, out, G);
}

// Round 11
// 291.226 us; speedup vs baseline: 1.2780x; 1.1968x over previous
//
#include <hip/hip_runtime.h>
#include <math.h>

#define D 128
#define NBUCK_MAX 1024     // runtime nbuck = ceil(N/128) = 782
#define NB_EDGE   256      // edge-chunk blocks for count/placement passes
#define CAPB 4096          // static slots per bucket (fill 2048 +- 45 sigma; deterministic input)

typedef unsigned short u16;
typedef unsigned int   u32;
typedef __attribute__((ext_vector_type(8))) short short8;   // 8 bf16 = 4 VGPRs (MFMA A/B frag)
typedef __attribute__((ext_vector_type(4))) float f32x4;    // MFMA C/D frag
typedef __attribute__((ext_vector_type(2))) float f32x2;

static __device__ __forceinline__ u16 f32_to_bf16(float f) {
    u32 u = __builtin_bit_cast(u32, f);
    u32 r = (u + 0x7FFFu + ((u >> 16) & 1u)) >> 16;          // RNE
    return (u16)r;
}
static __device__ __forceinline__ u32 pack_bf16x2(float lo, float hi) {
    return (u32)f32_to_bf16(lo) | ((u32)f32_to_bf16(hi) << 16);
}
static __device__ __forceinline__ float bf16lo_to_f32(u32 v) {
    return __builtin_bit_cast(float, v << 16);
}
static __device__ __forceinline__ float bf16hi_to_f32(u32 v) {
    return __builtin_bit_cast(float, v & 0xFFFF0000u);
}

// ---------------- dispatch 1: bucket_count + goff scan + W pack + Wf pack ----------------
__global__ __launch_bounds__(512) void prep_count(const int* __restrict__ dst, int E, int nbuck,
                                                  int* __restrict__ blockHist,
                                                  const float* __restrict__ W0, const float* __restrict__ W1,
                                                  u16* __restrict__ Wp0, u16* __restrict__ Wp1,
                                                  const float* __restrict__ Wf, float* __restrict__ Wfp,
                                                  const int* __restrict__ gsz, int G, int* __restrict__ goff) {
    const int b = blockIdx.x;
    const int tid = threadIdx.x;
    if (b < NB_EDGE) {
        __shared__ int h[NBUCK_MAX];
        for (int i = tid; i < nbuck; i += 512) h[i] = 0;
        __syncthreads();
        int per = (E + NB_EDGE - 1) / NB_EDGE;
        int s = b * per, e = min(E, s + per);
        for (int i = s + tid; i < e; i += 512) atomicAdd(&h[dst[i] >> 7], 1);
        __syncthreads();
        for (int i = tid; i < nbuck; i += 512) blockHist[b * nbuck + i] = h[i];
    } else if (b == NB_EDGE) {
        // exclusive scan of graph sizes -> goff[0..G] (sentinel)
        __shared__ int wsum[8];
        int base = tid * 4;
        int v[4];
        #pragma unroll
        for (int k = 0; k < 4; k++) v[k] = (base + k < G) ? gsz[base + k] : 0;
        int s = v[0] + v[1] + v[2] + v[3];
        int lane = tid & 63;
        int incl = s;
        #pragma unroll
        for (int off = 1; off < 64; off <<= 1) { int t = __shfl_up(incl, off); if (lane >= off) incl += t; }
        int wv = tid >> 6;
        if (lane == 63) wsum[wv] = incl;
        __syncthreads();
        int woff = 0;
        for (int w = 0; w < wv; w++) woff += wsum[w];
        int run = woff + incl - s;
        #pragma unroll
        for (int k = 0; k < 4; k++) {
            if (base + k <= G) goff[base + k] = run;
            run += v[k];
        }
    } else if (b == NB_EDGE + 1) {
        // Wf pack: Wfp[lane*24 + k*3 + j] = Wf[((lane&15)*8+k)*12 + 3*(lane>>4)+j]  (64 lanes x 24)
        for (int i = tid; i < 64 * 24; i += 512) {
            int lane = i / 24, r = i % 24, k = r / 3, j = r % 3;
            Wfp[i] = Wf[(((lane & 15) * 8) + k) * 12 + 3 * (lane >> 4) + j];
        }
    } else {
        // W pack: Wp[((nt*4+kt)*64 + lane)*8 + j] = bf16( W[kt*32+(lane>>4)*8+j][nt*16+(lane&15)] )
        int gidx = (b - (NB_EDGE + 2)) * 512 + tid;          // 0 .. 32767
        const float* W = (gidx < 128 * 128) ? W0 : W1;
        u16* Wp = (gidx < 128 * 128) ? Wp0 : Wp1;
        int idx = gidx & (128 * 128 - 1);
        int j = idx & 7, lane = (idx >> 3) & 63, kt = (idx >> 9) & 3, nt = idx >> 11;
        int k = kt * 32 + ((lane >> 4) << 3) + j;
        int n = nt * 16 + (lane & 15);
        Wp[idx] = f32_to_bf16(W[k * 128 + n]);
    }
}

// ---------------- dispatch 2: scan_blocks (per-bucket exclusive scan across NB_EDGE blocks) ----------------
__global__ __launch_bounds__(256) void scan_blocks(int* __restrict__ blockHist, int nbuck,
                                                   int* __restrict__ bucketTotal) {
    int bucket = (blockIdx.x * 256 + threadIdx.x) >> 6;
    int lane = threadIdx.x & 63;
    if (bucket >= nbuck) return;
    int carry = 0;
    #pragma unroll
    for (int c = 0; c < NB_EDGE / 64; c++) {
        int idx = (c * 64 + lane) * nbuck + bucket;
        int v = blockHist[idx];
        int incl = v;
        #pragma unroll
        for (int off = 1; off < 64; off <<= 1) { int t = __shfl_up(incl, off); if (lane >= off) incl += t; }
        blockHist[idx] = carry + incl - v;
        carry += __shfl(incl, 63);
    }
    if (lane == 0) bucketTotal[bucket] = carry;
}

// ---------------- dispatch 3: placement via LDS cursors (static bases b*CAPB) ----------------
__global__ __launch_bounds__(512) void bucket_place(const int* __restrict__ src, const int* __restrict__ dst,
                                                    int E, int nbuck, const int* __restrict__ blockHist,
                                                    u32* __restrict__ edgeBuf) {
    __shared__ int cur[NBUCK_MAX];
    int tid = threadIdx.x;
    for (int i = tid; i < nbuck; i += 512)
        cur[i] = i * CAPB + blockHist[blockIdx.x * nbuck + i];
    __syncthreads();
    int per = (E + NB_EDGE - 1) / NB_EDGE;
    int s = blockIdx.x * per, e = min(E, s + per);
    for (int i = s + tid; i < e; i += 512) {
        int d = dst[i];
        int b = d >> 7;
        int pos = atomicAdd(&cur[b], 1);
        edgeBuf[pos] = (u32)src[i] | ((u32)(d & 127) << 20);
    }
}

// ---------------- MFMA GEMM core ----------------
static __device__ __forceinline__ void gemm_body(const short8 af[4], const u16* __restrict__ Wp,
                                                 u16* __restrict__ outb, int N, int row0,
                                                 int tid, int wave, int lane, int quad, int l16,
                                                 u16* Cs) {
    f32x4 acc[8];
    #pragma unroll
    for (int nt = 0; nt < 8; nt++) acc[nt] = (f32x4){0.f, 0.f, 0.f, 0.f};
    #pragma unroll
    for (int kt = 0; kt < 4; kt++) {
        #pragma unroll
        for (int nt = 0; nt < 8; nt++) {
            short8 bf = *(const short8*)(Wp + ((size_t)(nt * 4 + kt) * 64 + lane) * 8);
            acc[nt] = __builtin_amdgcn_mfma_f32_16x16x32_bf16(af[kt], bf, acc[nt], 0, 0, 0);
        }
    }
    // C layout col=lane&15, row=quad*4+reg -> LDS transpose -> coalesced bf16 store
    #pragma unroll
    for (int nt = 0; nt < 8; nt++) {
        #pragma unroll
        for (int r = 0; r < 4; r++) {
            int rl = wave * 16 + quad * 4 + r;
            Cs[rl * 136 + nt * 16 + l16] = f32_to_bf16(acc[nt][r]);
        }
    }
    __syncthreads();
    for (int i = tid; i < 64 * 16; i += 256) {
        int row = i >> 4, chunk = i & 15;
        int grow = row0 + row;
        if (grow <= N)      // row N = zero pad row for agg tail lanes
            *(uint4*)(outb + (size_t)grow * 128 + chunk * 8) =
                *(const uint4*)(Cs + row * 136 + chunk * 8);
    }
}

// ---------------- dispatch 4: csr finalize (blocks 0..nbuck-1) + layer-0 gemm (blocks nbuck..) ----------------
__global__ __launch_bounds__(256) void finalize_gemm0(const u32* __restrict__ edgeBuf,
                                                      const int* __restrict__ bucketTotal,
                                                      int2* __restrict__ rowse, int* __restrict__ col_idx,
                                                      int nbuck,
                                                      const float* __restrict__ A, const u16* __restrict__ Wp,
                                                      u16* __restrict__ outb, int N) {
    __shared__ u16 Cs[64 * 136];
    const int tid = threadIdx.x;
    if ((int)blockIdx.x < nbuck) {
        int* hist = (int*)Cs;            // 128 ints
        int* lcur = ((int*)Cs) + 128;    // 128 ints
        const int b = blockIdx.x;
        const int start = b * CAPB;
        const int end = start + bucketTotal[b];
        if (tid < 128) hist[tid] = 0;
        __syncthreads();
        for (int i = start + tid; i < end; i += 256)
            atomicAdd(&hist[edgeBuf[i] >> 20], 1);
        __syncthreads();
        if (tid < 64) {
            int v0 = hist[tid * 2], v1 = hist[tid * 2 + 1];
            int s = v0 + v1;
            int incl = s;
            #pragma unroll
            for (int off = 1; off < 64; off <<= 1) { int t = __shfl_up(incl, off); if (tid >= off) incl += t; }
            int excl = incl - s;
            lcur[tid * 2] = excl;
            lcur[tid * 2 + 1] = excl + v0;
            int node = b * 128 + tid * 2;
            int st = start + excl;
            if (node < N) rowse[node] = make_int2(st, st + v0);
            if (node + 1 < N) rowse[node + 1] = make_int2(st + v0, st + v0 + v1);
        }
        __syncthreads();
        for (int i = start + tid; i < end; i += 256) {
            u32 p = edgeBuf[i];
            int pos = atomicAdd(&lcur[p >> 20], 1);
            col_idx[start + pos] = (int)(p & 0xFFFFFu);
        }
    } else {
        const int bid = blockIdx.x - nbuck;
        const int wave = tid >> 6, lane = tid & 63, quad = lane >> 4, l16 = lane & 15;
        const int row0 = bid * 64;
        const int arow = row0 + wave * 16 + l16;
        union { u32 u[4]; short8 s; } cv;
        short8 af[4];
        if (arow < N) {
            const float* ab = A + (size_t)arow * 128 + quad * 8;
            #pragma unroll
            for (int kt = 0; kt < 4; kt++) {
                float4 x0 = *(const float4*)(ab + kt * 32);
                float4 x1 = *(const float4*)(ab + kt * 32 + 4);
                cv.u[0] = pack_bf16x2(x0.x, x0.y);
                cv.u[1] = pack_bf16x2(x0.z, x0.w);
                cv.u[2] = pack_bf16x2(x1.x, x1.y);
                cv.u[3] = pack_bf16x2(x1.z, x1.w);
                af[kt] = cv.s;
            }
        } else {
            short8 z = {0, 0, 0, 0, 0, 0, 0, 0};
            #pragma unroll
            for (int kt = 0; kt < 4; kt++) af[kt] = z;
        }
        gemm_body(af, Wp, outb, N, row0, tid, wave, lane, quad, l16, Cs);
    }
}

// dispatch 6: layer-1 GEMM, bf16 A
__global__ __launch_bounds__(256) void gemm_mfma(const u16* __restrict__ A, const u16* __restrict__ Wp,
                                                 u16* __restrict__ outb, int N) {
    __shared__ u16 Cs[64 * 136];
    const int tid = threadIdx.x;
    const int wave = tid >> 6, lane = tid & 63, quad = lane >> 4, l16 = lane & 15;
    const int row0 = blockIdx.x * 64;
    const int arow = row0 + wave * 16 + l16;
    short8 af[4];
    if (arow < N) {
        const u16* ab = A + (size_t)arow * 128 + quad * 8;
        #pragma unroll
        for (int kt = 0; kt < 4; kt++) af[kt] = *(const short8*)(ab + kt * 32);
    } else {
        short8 z = {0, 0, 0, 0, 0, 0, 0, 0};
        #pragma unroll
        for (int kt = 0; kt < 4; kt++) af[kt] = z;
    }
    gemm_body(af, Wp, outb, N, row0, tid, wave, lane, quad, l16, Cs);
}

// ---------------- shared gather core: returns relu(sum + self + bias) slice in r[8] ----------------
static __device__ __forceinline__ void add_row(f32x2* acc, uint4 u) {
    acc[0] += (f32x2){bf16lo_to_f32(u.x), bf16hi_to_f32(u.x)};
    acc[1] += (f32x2){bf16lo_to_f32(u.y), bf16hi_to_f32(u.y)};
    acc[2] += (f32x2){bf16lo_to_f32(u.z), bf16hi_to_f32(u.z)};
    acc[3] += (f32x2){bf16lo_to_f32(u.w), bf16hi_to_f32(u.w)};
}

static __device__ __forceinline__ void gather_core(const u16* __restrict__ xwb, const int2* __restrict__ rowse,
                                                   const int* __restrict__ col_idx, const float* __restrict__ bias,
                                                   int wid, int lane, int N, int q, int d8, float r[8]) {
    f32x2 acc[4];
    #pragma unroll
    for (int t = 0; t < 4; t++) acc[t] = (f32x2){0.f, 0.f};
    int2 se = rowse[wid];
    int start = se.x, end = se.y;
    for (int e = start; e < end; e += 64) {
        int idx = e + lane;
        int j = (idx < end) ? col_idx[idx] : N;   // tail -> shared zero row
        int cnt = min(64, end - e);
        for (int i = 0; i < cnt; i += 16) {
            int j0 = __shfl(j, i + q);
            int j1 = __shfl(j, i + 4 + q);
            int j2 = __shfl(j, i + 8 + q);
            int j3 = __shfl(j, i + 12 + q);
            uint4 r0 = *(const uint4*)(xwb + (size_t)j0 * D + d8);
            uint4 r1 = *(const uint4*)(xwb + (size_t)j1 * D + d8);
            uint4 r2 = *(const uint4*)(xwb + (size_t)j2 * D + d8);
            uint4 r3 = *(const uint4*)(xwb + (size_t)j3 * D + d8);
            add_row(acc, r0);
            add_row(acc, r1);
            add_row(acc, r2);
            add_row(acc, r3);
        }
    }
    float av[8] = {acc[0].x, acc[0].y, acc[1].x, acc[1].y, acc[2].x, acc[2].y, acc[3].x, acc[3].y};
    #pragma unroll
    for (int t = 0; t < 8; t++) {
        av[t] += __shfl_xor(av[t], 16);
        av[t] += __shfl_xor(av[t], 32);
    }
    uint4 sv = *(const uint4*)(xwb + (size_t)wid * D + d8);
    float4 ba = *(const float4*)(bias + d8);
    float4 bb = *(const float4*)(bias + d8 + 4);
    r[0] = fmaxf(av[0] + bf16lo_to_f32(sv.x) + ba.x, 0.f);
    r[1] = fmaxf(av[1] + bf16hi_to_f32(sv.x) + ba.y, 0.f);
    r[2] = fmaxf(av[2] + bf16lo_to_f32(sv.y) + ba.z, 0.f);
    r[3] = fmaxf(av[3] + bf16hi_to_f32(sv.y) + ba.w, 0.f);
    r[4] = fmaxf(av[4] + bf16lo_to_f32(sv.z) + bb.x, 0.f);
    r[5] = fmaxf(av[5] + bf16hi_to_f32(sv.z) + bb.y, 0.f);
    r[6] = fmaxf(av[6] + bf16lo_to_f32(sv.w) + bb.z, 0.f);
    r[7] = fmaxf(av[7] + bf16hi_to_f32(sv.w) + bb.w, 0.f);
}

// dispatch 5: layer-1 aggregate, stores bf16 h
__global__ __launch_bounds__(256) void agg_relu(const u16* __restrict__ xwb, const int2* __restrict__ rowse,
                                                const int* __restrict__ col_idx, const float* __restrict__ bias,
                                                u16* __restrict__ outh, int N) {
    int wid = (blockIdx.x * 256 + threadIdx.x) >> 6;
    int lane = threadIdx.x & 63;
    if (wid >= N) return;
    const int q = lane >> 4;
    const int d8 = (lane & 15) * 8;
    float r[8];
    gather_core(xwb, rowse, col_idx, bias, wid, lane, N, q, d8, r);
    if (q == 0) {
        uint4 o;
        o.x = pack_bf16x2(r[0], r[1]);
        o.y = pack_bf16x2(r[2], r[3]);
        o.z = pack_bf16x2(r[4], r[5]);
        o.w = pack_bf16x2(r[6], r[7]);
        *(uint4*)(outh + (size_t)wid * D + d8) = o;
    }
}

// dispatch 7: layer-2 aggregate fused with head; writes sigmoid logits to out12[node][12]
// Wfp is per-lane-contiguous (24 floats/lane, coalesced float4 loads issued BEFORE the gather).
__global__ __launch_bounds__(256) void agg_head(const u16* __restrict__ xwb, const int2* __restrict__ rowse,
                                                const int* __restrict__ col_idx, const float* __restrict__ bias,
                                                const float* __restrict__ Wfp, const float* __restrict__ bfv,
                                                float* __restrict__ out12, int N) {
    int wid = (blockIdx.x * 256 + threadIdx.x) >> 6;
    int lane = threadIdx.x & 63;
    if (wid >= N) return;
    const int q = lane >> 4;
    const int d8 = (lane & 15) * 8;
    // issue head-weight loads early (independent of gather) — 6 coalesced float4
    float w[24];
    const float* wp = Wfp + lane * 24;
    #pragma unroll
    for (int i = 0; i < 6; i++) *(float4*)(w + i * 4) = *(const float4*)(wp + i * 4);
    float r[8];
    gather_core(xwb, rowse, col_idx, bias, wid, lane, N, q, d8, r);
    // head: tasks t0..t0+2 for this quarter; w[k*3+j] = Wf[d8+k][t0+j]
    const int t0 = 3 * q;
    float p0 = 0.f, p1 = 0.f, p2 = 0.f;
    #pragma unroll
    for (int k = 0; k < 8; k++) {
        p0 += r[k] * w[k * 3];
        p1 += r[k] * w[k * 3 + 1];
        p2 += r[k] * w[k * 3 + 2];
    }
    #pragma unroll
    for (int m = 1; m <= 8; m <<= 1) {
        p0 += __shfl_xor(p0, m);
        p1 += __shfl_xor(p1, m);
        p2 += __shfl_xor(p2, m);
    }
    if ((lane & 15) == 0) {
        float s0 = 1.f / (1.f + __expf(-(p0 + bfv[t0])));
        float s1 = 1.f / (1.f + __expf(-(p1 + bfv[t0 + 1])));
        float s2 = 1.f / (1.f + __expf(-(p2 + bfv[t0 + 2])));
        float* o = out12 + (size_t)wid * 12 + t0;
        o[0] = s0; o[1] = s1; o[2] = s2;
    }
}

// dispatch 8: per-graph mean over out12
__global__ __launch_bounds__(128) void graph_mean(const float* __restrict__ out12, const int* __restrict__ goff,
                                                  float* __restrict__ out, int G) {
    __shared__ float partial[120];
    int g = blockIdx.x;
    int tid = threadIdx.x;
    int start = goff[g];
    int size = goff[g + 1] - start;
    if (tid < 120) {
        int t = tid % 12, chunk = tid / 12;
        float s = 0.f;
        for (int i = chunk; i < size; i += 10)
            s += out12[(size_t)(start + i) * 12 + t];
        partial[tid] = s;
    }
    __syncthreads();
    if (tid < 12) {
        float tot = 0.f;
        #pragma unroll
        for (int c = 0; c < 10; c++) tot += partial[c * 12 + tid];
        out[(size_t)g * 12 + tid] = tot / (float)size;
    }
}

// ---------------- launch ----------------

extern "C" void kernel_launch(void* const* d_in, const int* in_sizes, int n_in,
                              void* d_out, int out_size, void* d_ws, size_t ws_size,
                              hipStream_t stream) {
    const float* X   = (const float*)d_in[0];
    const int* edges = (const int*)d_in[1];
    const int* gsz   = (const int*)d_in[2];
    const float* W0  = (const float*)d_in[3];
    const float* b0  = (const float*)d_in[4];
    const float* W1  = (const float*)d_in[5];
    const float* b1  = (const float*)d_in[6];
    const float* Wf  = (const float*)d_in[7];
    const float* bfv = (const float*)d_in[8];
    float* out = (float*)d_out;

    const int N = in_sizes[0] / D;       // 100000
    const int E = in_sizes[1] / 2;       // 1600000
    const int G = in_sizes[2];           // 1000
    const int* esrc = edges;
    const int* edst = edges + E;
    const int nbuck = (N + 127) >> 7;    // 782

    // workspace layout (xwb/hb get N+64 rows: row N is the zero pad row)
    char* ws = (char*)d_ws;
    char* p = ws;
    u16* xwb     = (u16*)p;  p += (((size_t)(N + 64) * D * 2) + 255) & ~255ull;
    u16* hb      = (u16*)p;  p += (((size_t)(N + 64) * D * 2) + 255) & ~255ull;
    u16* Wp0     = (u16*)p;  p += ((size_t)128 * 128 * 2 + 255) & ~255ull;
    u16* Wp1     = (u16*)p;  p += ((size_t)128 * 128 * 2 + 255) & ~255ull;
    float* Wfp   = (float*)p; p += ((size_t)64 * 24 * 4 + 255) & ~255ull;
    u32* edgeBuf = (u32*)p;  p += (((size_t)nbuck * CAPB * 4) + 255) & ~255ull;   // 12.8 MB
    int* col_idx = (int*)p;  p += (((size_t)nbuck * CAPB * 4) + 255) & ~255ull;   // 12.8 MB
    int2* rowse  = (int2*)p; p += (((size_t)N * 8) + 255) & ~255ull;
    float* out12 = (float*)p; p += (((size_t)N * 12 * 4) + 255) & ~255ull;        // 4.8 MB
    int* blockHist   = (int*)p; p += ((size_t)NB_EDGE * NBUCK_MAX * 4 + 255) & ~255ull;
    int* bucketTotal = (int*)p; p += ((size_t)NBUCK_MAX * 4 + 255) & ~255ull;
    int* goff        = (int*)p;

    // 1: bucket count + goff scan + Wf pack + W pack
    prep_count<<<NB_EDGE + 2 + 64, 512, 0, stream>>>(edst, E, nbuck, blockHist,
                                                     W0, W1, Wp0, Wp1, Wf, Wfp, gsz, G, goff);
    // 2: per-bucket block-scan
    scan_blocks<<<(nbuck * 64 + 255) / 256, 256, 0, stream>>>(blockHist, nbuck, bucketTotal);
    // 3: placement (LDS cursors, static bases)
    bucket_place<<<NB_EDGE, 512, 0, stream>>>(esrc, edst, E, nbuck, blockHist, edgeBuf);
    // 4: per-bucket CSR finalize + layer-0 GEMM (fp32 A, fused cast)
    const int gemmGrid = (N + 63) / 64;
    finalize_gemm0<<<nbuck + gemmGrid, 256, 0, stream>>>(edgeBuf, bucketTotal, rowse, col_idx, nbuck,
                                                         X, Wp0, xwb, N);
    // 5: layer-1 aggregate
    agg_relu<<<(N * 64 + 255) / 256, 256, 0, stream>>>(xwb, rowse, col_idx, b0, hb, N);
    // 6: layer-1 GEMM
    gemm_mfma<<<gemmGrid, 256, 0, stream>>>(hb, Wp1, xwb, N);
    // 7: layer-2 aggregate fused with head -> out12 (coalesced weights + coalesced stores)
    agg_head<<<(N * 64 + 255) / 256, 256, 0, stream>>>(xwb, rowse, col_idx, b1, Wfp, bfv, out12, N);
    // 8: per-graph mean
    graph_mean<<<G, 128, 0, stream>>>(out12, goff, out, G);
}